// Round 5
// baseline (254.035 us; speedup 1.0000x reference)
//
#include <hip/hip_runtime.h>
#include <math.h>

namespace {
constexpr int BB = 8;
constexpr int CH = 256;
constexpr int NN = 4096;
}

typedef float f32x4 __attribute__((ext_vector_type(4)));
typedef short bf16x8 __attribute__((ext_vector_type(8)));
typedef unsigned short us8 __attribute__((ext_vector_type(8)));

#define MFMA16(a, b, c) __builtin_amdgcn_mfma_f32_16x16x32_bf16(a, b, c, 0, 0, 0)

__device__ __forceinline__ unsigned short f2bf(float x) {
    unsigned int u = __float_as_uint(x);
    u += 0x7fffu + ((u >> 16) & 1u);
    return (unsigned short)(u >> 16);
}
__device__ __forceinline__ float bf2f(unsigned short h) {
    return __uint_as_float(((unsigned int)h) << 16);
}

// ---------------------------------------------------------------------------
// Kernel 0: split W (wq|wk|wv, 320x256) into bf16 hi/lo.
// ---------------------------------------------------------------------------
__global__ __launch_bounds__(256) void wsplit_kernel(
    const float* __restrict__ wq, const float* __restrict__ wk,
    const float* __restrict__ wv,
    unsigned short* __restrict__ wh, unsigned short* __restrict__ wl)
{
    int idx = blockIdx.x * 256 + threadIdx.x;   // 0..81919
    float v;
    if (idx < 8192)       v = wq[idx];
    else if (idx < 16384) v = wk[idx - 8192];
    else                  v = wv[idx - 16384];
    unsigned short hi = f2bf(v);
    wh[idx] = hi;
    wl[idx] = f2bf(v - bf2f(hi));
}

// ---------------------------------------------------------------------------
// Kernel 1: fused transpose + proj GEMM (MFMA, 3-term hi/lo split).
// Phase 1: VGPR global loads (no DMA barriers), convert, write bf16 hi/lo
// [64n][256c] chunk-XOR-swizzled to LDS. Phase 2: MFMA K-loop (W direct from
// global). Epilogue -> qh/ql/kh/kl [b][n][32], vt [b][c][n].
// ---------------------------------------------------------------------------
#define PJ_XH 0
#define PJ_XL 32768
#define PJ_VE 0        // epilogue aliases (after barrier)
#define PJ_QK 36864

__global__ __launch_bounds__(256, 2) void proj_kernel(
    const float* __restrict__ x,
    const unsigned short* __restrict__ wh, const unsigned short* __restrict__ wl,
    const float* __restrict__ bq, const float* __restrict__ bk,
    const float* __restrict__ bv,
    unsigned short* __restrict__ qh, unsigned short* __restrict__ ql,
    unsigned short* __restrict__ kh, unsigned short* __restrict__ kl,
    unsigned short* __restrict__ vt)
{
    __shared__ __align__(16) unsigned char smem[65536];
    const int t    = threadIdx.x;
    const int lane = t & 63;
    const int w    = t >> 6;
    const int l16  = lane & 15;
    const int quad = lane >> 4;
    const int b    = blockIdx.x >> 6;
    const int n0   = (blockIdx.x & 63) << 6;

    // ---- phase 1: thread (cc=t&15, pg=t>>4) loads 16 channels x 4 pixels
    const int cc = t & 15, pg = t >> 4;
    const float* xg = x + (size_t)b * 256 * NN + n0 + pg * 4;
    float4 xv[16];
    #pragma unroll
    for (int jc = 0; jc < 16; ++jc)
        xv[jc] = *(const float4*)(xg + (size_t)(jc * 16 + cc) * NN);
    #pragma unroll
    for (int jc = 0; jc < 16; ++jc) {
        const int c = jc * 16 + cc;
        const int chunkb = c >> 3, cb = (c & 7) * 2;
        #pragma unroll
        for (int p = 0; p < 4; ++p) {
            const int n = pg * 4 + p;
            float v = (p == 0) ? xv[jc].x : (p == 1) ? xv[jc].y
                    : (p == 2) ? xv[jc].z : xv[jc].w;
            unsigned short hi = f2bf(v);
            unsigned short lo = f2bf(v - bf2f(hi));
            int off = n * 512 + ((chunkb ^ (n & 7)) * 16) + cb;
            *(unsigned short*)(smem + PJ_XH + off) = hi;
            *(unsigned short*)(smem + PJ_XL + off) = lo;
        }
    }
    __syncthreads();

    // ---- phase 2: K-loop. Wave w owns och-tiles w*5..w*5+4 (0-63 q/k, 64-319 v)
    f32x4 acc[5][4] = {};
    #pragma unroll 1
    for (int kc = 0; kc < 8; ++kc) {
        bf16x8 ah[5], al[5];
        #pragma unroll
        for (int i = 0; i < 5; ++i) {
            int och = (w * 5 + i) * 16 + l16;
            ah[i] = *(const bf16x8*)(wh + och * 256 + kc * 32 + quad * 8);
            al[i] = *(const bf16x8*)(wl + och * 256 + kc * 32 + quad * 8);
        }
        #pragma unroll
        for (int nt = 0; nt < 4; ++nt) {
            int roff = (nt * 16 + l16) * 512 + (((kc * 4 + quad) ^ (l16 & 7)) * 16);
            bf16x8 bh = *(const bf16x8*)(smem + PJ_XH + roff);
            bf16x8 bl = *(const bf16x8*)(smem + PJ_XL + roff);
            #pragma unroll
            for (int i = 0; i < 5; ++i) {
                acc[i][nt] = MFMA16(ah[i], bh, acc[i][nt]);
                acc[i][nt] = MFMA16(al[i], bh, acc[i][nt]);
                acc[i][nt] = MFMA16(ah[i], bl, acc[i][nt]);
            }
        }
    }
    __syncthreads();   // LDS reads done; alias epilogue regions

    // ---- epilogue
    #pragma unroll
    for (int i = 0; i < 5; ++i) {
        int tile = w * 5 + i;
        if (tile < 4) {  // q/k tiles (wave 0 only)
            #pragma unroll
            for (int r = 0; r < 4; ++r) {
                int och = tile * 16 + quad * 4 + r;
                float bias = (och < 32) ? bq[och] : bk[och - 32];
                int arr = (och < 32) ? 0 : 2;
                int oq = och & 31;
                #pragma unroll
                for (int nt = 0; nt < 4; ++nt) {
                    float val = acc[i][nt][r] + bias;
                    unsigned short hi = f2bf(val);
                    unsigned short lo = f2bf(val - bf2f(hi));
                    *(unsigned short*)(smem + PJ_QK + arr * 4096 + (nt * 16 + l16) * 64 + oq * 2) = hi;
                    *(unsigned short*)(smem + PJ_QK + (arr + 1) * 4096 + (nt * 16 + l16) * 64 + oq * 2) = lo;
                }
            }
        } else {          // v tiles
            #pragma unroll
            for (int r = 0; r < 4; ++r) {
                int voch = tile * 16 + quad * 4 + r - 64;
                float bias = bv[voch];
                #pragma unroll
                for (int nt = 0; nt < 4; ++nt) {
                    *(unsigned short*)(smem + PJ_VE + voch * 136 + (nt * 16 + l16) * 2)
                        = f2bf(acc[i][nt][r] + bias);
                }
            }
        }
    }
    __syncthreads();

    {   // copy-out q/k: 4 arrays x 64 rows x 64B
        unsigned short* dsts[4] = { qh, ql, kh, kl };
        int arr = t >> 6, rn = t & 63;
        unsigned short* dst = dsts[arr] + ((size_t)b * NN + n0 + rn) * 32;
        #pragma unroll
        for (int i = 0; i < 4; ++i)
            *(us8*)(dst + i * 8) = *(const us8*)(smem + PJ_QK + arr * 4096 + rn * 64 + i * 16);
    }
    #pragma unroll
    for (int p = 0; p < 4; ++p) {   // copy-out v: 256 rows x 128B
        int voch = p * 64 + (t >> 2), piece = t & 3;
        unsigned short* dst = vt + ((size_t)b * CH + voch) * NN + n0 + piece * 16;
        *(us8*)(dst)     = *(const us8*)(smem + PJ_VE + voch * 136 + piece * 32);
        *(us8*)(dst + 8) = *(const us8*)(smem + PJ_VE + voch * 136 + piece * 32 + 16);
    }
}

// ---------------------------------------------------------------------------
// Kernel 2: MFMA flash attention. 64-key rounds; K/V fragments loaded
// DIRECTLY global->VGPR in MFMA B-layout (no LDS staging, no vmcnt(0) drain
// at barriers -> prefetch rides across rounds). LDS only holds P (ping-pong,
// pad 144B) + S. One barrier per round.
// E: wave w owns keys [w*16,w*16+16) x all 64 queries (zero K redundancy).
// PV: wave w owns all 64 queries x channels [w*64,w*64+64).
// ---------------------------------------------------------------------------
#define AP_PAD 144
#define AS_OFF 18432    // after 2 x 64 x 144 P buffers

__global__ __launch_bounds__(256, 2) void attn_kernel(
    const unsigned short* __restrict__ qh, const unsigned short* __restrict__ ql,
    const unsigned short* __restrict__ kh, const unsigned short* __restrict__ kl,
    const unsigned short* __restrict__ vt, const float* __restrict__ gptr,
    float* __restrict__ out)
{
    __shared__ __align__(16) unsigned char smem[19456];
    const int t    = threadIdx.x;
    const int lane = t & 63;
    const int w    = t >> 6;
    const int l16  = lane & 15;
    const int quad = lane >> 4;
    const int b    = blockIdx.x & 7;            // batch -> XCD swizzle
    const int n0   = (blockIdx.x >> 3) << 6;

    // Q A-frags for all 4 query sub-tiles (hi/lo), held all kernel
    bf16x8 qhA[4], qlA[4];
    #pragma unroll
    for (int qt = 0; qt < 4; ++qt) {
        size_t row = (size_t)b * NN + n0 + qt * 16 + l16;
        qhA[qt] = *(const bf16x8*)(qh + row * 32 + quad * 8);
        qlA[qt] = *(const bf16x8*)(ql + row * 32 + quad * 8);
    }

    // per-thread global fragment pointers
    const unsigned char* kp  = (const unsigned char*)kh
        + ((size_t)b * NN + w * 16 + l16) * 64 + quad * 16;
    const unsigned char* klp = (const unsigned char*)kl
        + ((size_t)b * NN + w * 16 + l16) * 64 + quad * 16;
    const unsigned char* vp  = (const unsigned char*)vt
        + ((size_t)b * CH + w * 64 + l16) * (NN * 2) + quad * 16;

    bf16x8 kfh[2], kfl[2], vf[2][8];
    kfh[0] = *(const bf16x8*)kp;
    kfl[0] = *(const bf16x8*)klp;

    f32x4 acc[4][4] = {};
    float S[4][4] = {};

    #pragma unroll 2
    for (int r = 0; r < 64; ++r) {
        // prefetch K(r+1) into the other ping-pong slot
        if (r < 63) {
            kfh[(r + 1) & 1] = *(const bf16x8*)(kp  + (size_t)(r + 1) * 4096);
            kfl[(r + 1) & 1] = *(const bf16x8*)(klp + (size_t)(r + 1) * 4096);
        }
        // load V(r) (consumed by PV next round)
        #pragma unroll
        for (int ct = 0; ct < 4; ++ct)
            #pragma unroll
            for (int ks = 0; ks < 2; ++ks)
                vf[r & 1][ct * 2 + ks] = *(const bf16x8*)
                    (vp + (size_t)ct * 131072 + ks * 64 + (size_t)r * 128);

        // E(r): wave's 16 keys x all 64 queries -> P[r&1]
        {
            unsigned char* pb = smem + (r & 1) * 9216;
            const bf16x8 bh = kfh[r & 1], bl = kfl[r & 1];
            #pragma unroll
            for (int qt = 0; qt < 4; ++qt) {
                f32x4 e = { 0.f, 0.f, 0.f, 0.f };
                e = MFMA16(qhA[qt], bh, e);
                e = MFMA16(qlA[qt], bh, e);
                e = MFMA16(qhA[qt], bl, e);
                #pragma unroll
                for (int rr = 0; rr < 4; ++rr) {
                    float p = __expf(e[rr]);   // |e| << 88: no max needed
                    unsigned short pv16 = f2bf(p);
                    S[qt][rr] += bf2f(pv16);   // numerator-consistent S
                    *(unsigned short*)(pb + (qt * 16 + quad * 4 + rr) * AP_PAD
                                          + (w * 16 + l16) * 2) = pv16;
                }
            }
        }
        // PV(r-1): all 64 q x wave's 64 channels, P from LDS, V from regs
        if (r > 0) {
            const unsigned char* pp = smem + ((r - 1) & 1) * 9216;
            #pragma unroll
            for (int ks = 0; ks < 2; ++ks) {
                bf16x8 aP[4];
                #pragma unroll
                for (int qt = 0; qt < 4; ++qt)
                    aP[qt] = *(const bf16x8*)(pp + (qt * 16 + l16) * AP_PAD
                                                 + ks * 64 + quad * 16);
                #pragma unroll
                for (int qt = 0; qt < 4; ++qt)
                    #pragma unroll
                    for (int ct = 0; ct < 4; ++ct)
                        acc[qt][ct] = MFMA16(aP[qt], vf[(r - 1) & 1][ct * 2 + ks],
                                             acc[qt][ct]);
            }
        }
        __syncthreads();
    }
    {   // final PV(63): P[1], vf[1]
        const unsigned char* pp = smem + 9216;
        #pragma unroll
        for (int ks = 0; ks < 2; ++ks) {
            bf16x8 aP[4];
            #pragma unroll
            for (int qt = 0; qt < 4; ++qt)
                aP[qt] = *(const bf16x8*)(pp + (qt * 16 + l16) * AP_PAD
                                             + ks * 64 + quad * 16);
            #pragma unroll
            for (int qt = 0; qt < 4; ++qt)
                #pragma unroll
                for (int ct = 0; ct < 4; ++ct)
                    acc[qt][ct] = MFMA16(aP[qt], vf[1][ct * 2 + ks], acc[qt][ct]);
        }
    }

    // S: reduce over this wave's 16 key-lanes, publish per (wave, query)
    #pragma unroll
    for (int mask = 1; mask <= 8; mask <<= 1)
        #pragma unroll
        for (int qt = 0; qt < 4; ++qt)
            #pragma unroll
            for (int rr = 0; rr < 4; ++rr)
                S[qt][rr] += __shfl_xor(S[qt][rr], mask);
    float* SM = (float*)(smem + AS_OFF);
    if (l16 == 0) {
        #pragma unroll
        for (int qt = 0; qt < 4; ++qt)
            #pragma unroll
            for (int rr = 0; rr < 4; ++rr)
                SM[w * 64 + qt * 16 + quad * 4 + rr] = S[qt][rr];
    }
    __syncthreads();

    const float g1 = 1.f + gptr[0];
    float* ob = out + (size_t)b * CH * NN;
    #pragma unroll
    for (int qt = 0; qt < 4; ++qt) {
        float is[4];
        #pragma unroll
        for (int rr = 0; rr < 4; ++rr) {
            int qi = qt * 16 + quad * 4 + rr;
            float Sf = SM[qi] + SM[64 + qi] + SM[128 + qi] + SM[192 + qi];
            is[rr] = g1 / Sf;
        }
        #pragma unroll
        for (int ct = 0; ct < 4; ++ct) {
            float4 o4;
            o4.x = floorf(acc[qt][ct][0] * is[0] * 256.f) * 0.00390625f;
            o4.y = floorf(acc[qt][ct][1] * is[1] * 256.f) * 0.00390625f;
            o4.z = floorf(acc[qt][ct][2] * is[2] * 256.f) * 0.00390625f;
            o4.w = floorf(acc[qt][ct][3] * is[3] * 256.f) * 0.00390625f;
            *(float4*)(ob + (size_t)(w * 64 + ct * 16 + l16) * NN
                          + n0 + qt * 16 + quad * 4) = o4;
        }
    }
}

// ---------------------------------------------------------------------------
extern "C" void kernel_launch(void* const* d_in, const int* in_sizes, int n_in,
                              void* d_out, int out_size, void* d_ws, size_t ws_size,
                              hipStream_t stream) {
    const float* x  = (const float*)d_in[0];
    const float* wq = (const float*)d_in[1];
    const float* bq = (const float*)d_in[2];
    const float* wk = (const float*)d_in[3];
    const float* bk = (const float*)d_in[4];
    const float* wv = (const float*)d_in[5];
    const float* bv = (const float*)d_in[6];
    const float* gm = (const float*)d_in[7];
    float* out = (float*)d_out;

    unsigned short* ws = (unsigned short*)d_ws;
    const size_t WSZ = 320 * 256;
    const size_t QSZ = (size_t)BB * NN * 32;
    unsigned short* wh = ws;
    unsigned short* wl = wh + WSZ;
    unsigned short* qh = wl + WSZ;
    unsigned short* ql = qh + QSZ;
    unsigned short* kh = ql + QSZ;
    unsigned short* kl = kh + QSZ;
    unsigned short* vt = kl + QSZ;

    wsplit_kernel<<<320, 256, 0, stream>>>(wq, wk, wv, wh, wl);
    proj_kernel<<<512, 256, 0, stream>>>(x, wh, wl, bq, bk, bv,
                                         qh, ql, kh, kl, vt);
    attn_kernel<<<512, 256, 0, stream>>>(qh, ql, kh, kl, vt, gm, out);
}